// Round 1
// baseline (219.197 us; speedup 1.0000x reference)
//
#include <hip/hip_runtime.h>

typedef unsigned short u16;
typedef __attribute__((ext_vector_type(8))) short short8;
typedef __attribute__((ext_vector_type(4))) float f32x4;
typedef __attribute__((ext_vector_type(4))) unsigned short u16x4;
typedef __attribute__((ext_vector_type(4))) float float4v;

__device__ __forceinline__ u16 f2bf(float f) {
  union { float f; unsigned u; } v; v.f = f;
  unsigned r = v.u + 0x7FFFu + ((v.u >> 16) & 1u);
  return (u16)(r >> 16);
}

__device__ __forceinline__ void gload16(const void* g, void* l) {
  __builtin_amdgcn_global_load_lds(
      (const __attribute__((address_space(1))) unsigned int*)g,
      (__attribute__((address_space(3))) unsigned int*)l, 16, 0, 0);
}

// ---------------- conversion kernels ----------------

// X fp32 [8192,1024] -> bf16 linear
__global__ __launch_bounds__(256) void kconv_x(const float* __restrict__ X,
                                               u16* __restrict__ Xb) {
  size_t i = ((size_t)blockIdx.x * 256 + threadIdx.x) * 4;
  float4v v = *(const float4v*)(X + i);
  u16x4 o;
  o.x = f2bf(v.x); o.y = f2bf(v.y); o.z = f2bf(v.z); o.w = f2bf(v.w);
  *(u16x4*)(Xb + i) = o;
}

// W fp32 [K=1024][N=1024] -> Wt bf16 [N][K], z selects Wq/Wk/Wv
__global__ __launch_bounds__(256) void kconv_wt(const float* __restrict__ Wq,
                                                const float* __restrict__ Wk,
                                                const float* __restrict__ Wv,
                                                u16* __restrict__ Wt) {
  __shared__ float tile[32][33];
  const float* W = blockIdx.z == 0 ? Wq : (blockIdx.z == 1 ? Wk : Wv);
  u16* O = Wt + (size_t)blockIdx.z * 1024 * 1024;
  int tx = threadIdx.x, ty = threadIdx.y;
  int n0 = blockIdx.x * 32, k0 = blockIdx.y * 32;
#pragma unroll
  for (int r = 0; r < 32; r += 8)
    tile[ty + r][tx] = W[(size_t)(k0 + ty + r) * 1024 + n0 + tx];
  __syncthreads();
#pragma unroll
  for (int r = 0; r < 32; r += 8)
    O[(size_t)(n0 + ty + r) * 1024 + k0 + tx] = f2bf(tile[tx][ty + r]);
}

// ---------------- GEMM core (m97 structure) ----------------
// C[128x128] += A[M,K] * Bt[N,K]^T  ; BK=32, 256 threads = 4 waves (2x2),
// each wave 64x64 as 4x4 frags of mfma_f32_16x16x32_bf16.
__device__ __forceinline__ void gemm_inner(const u16* __restrict__ A,
                                           const u16* __restrict__ B,
                                           int lda, int ldb,
                                           int rowBase, int colBase, int kIters,
                                           u16* As, u16* Bs, f32x4 acc[4][4]) {
  const int t = threadIdx.x;
  const int wid = t >> 6, lane = t & 63;
  const int wm = wid >> 1, wn = wid & 1;
  const int lrow = lane & 15, kseg = (lane >> 4) * 8;
  // staging: thread t loads rows (t>>2) and (t>>2)+64, 8 bf16 at col (t&3)*8
  const u16* ga = A + (size_t)(rowBase + (t >> 2)) * lda + ((t & 3) * 8);
  const u16* gb = B + (size_t)(colBase + (t >> 2)) * ldb + ((t & 3) * 8);
  u16* la0 = As + wid * 512;
  u16* la1 = As + 2048 + wid * 512;
  u16* lb0 = Bs + wid * 512;
  u16* lb1 = Bs + 2048 + wid * 512;
  const size_t a64 = (size_t)64 * lda, b64 = (size_t)64 * ldb;

  for (int kt = 0; kt < kIters; ++kt) {
    const int k0 = kt * 32;
    gload16(ga + k0, la0);
    gload16(ga + a64 + k0, la1);
    gload16(gb + k0, lb0);
    gload16(gb + b64 + k0, lb1);
    __syncthreads();  // drains vmcnt before barrier (compiler-inserted)
    short8 a[4], b[4];
#pragma unroll
    for (int mi = 0; mi < 4; mi++)
      a[mi] = *(const short8*)(As + (wm * 64 + mi * 16 + lrow) * 32 + kseg);
#pragma unroll
    for (int ni = 0; ni < 4; ni++)
      b[ni] = *(const short8*)(Bs + (wn * 64 + ni * 16 + lrow) * 32 + kseg);
#pragma unroll
    for (int mi = 0; mi < 4; mi++)
#pragma unroll
      for (int ni = 0; ni < 4; ni++)
        acc[mi][ni] = __builtin_amdgcn_mfma_f32_16x16x32_bf16(
            a[mi], b[ni], acc[mi][ni], 0, 0, 0);
    __syncthreads();
  }
}

// ---------------- QKV projection ----------------
// z=0 -> Q bf16 [8192,1024]; z=1 -> K; z=2 -> Vt bf16 [b][1024][2048] transposed
__global__ __launch_bounds__(256) void kqkv(const u16* __restrict__ Xb,
                                            const u16* __restrict__ Wt,
                                            u16* __restrict__ Qb,
                                            u16* __restrict__ Kb,
                                            u16* __restrict__ Vt) {
  __shared__ __align__(16) u16 As[4096];
  __shared__ __align__(16) u16 Bs[4096];
  const f32x4 z4 = {0.f, 0.f, 0.f, 0.f};
  f32x4 acc[4][4];
#pragma unroll
  for (int i = 0; i < 4; i++)
#pragma unroll
    for (int j = 0; j < 4; j++) acc[i][j] = z4;

  const int z = blockIdx.z;
  const int rowBase = blockIdx.y * 128, colBase = blockIdx.x * 128;
  const u16* Bt = Wt + (size_t)z * 1024 * 1024;
  gemm_inner(Xb, Bt, 1024, 1024, rowBase, colBase, 32, As, Bs, acc);

  const int t = threadIdx.x, wid = t >> 6, lane = t & 63;
  const int wm = wid >> 1, wn = wid & 1;
  const int r0 = rowBase + wm * 64 + ((lane >> 4) * 4);
  const int c0 = colBase + wn * 64 + (lane & 15);
  if (z < 2) {
    u16* O = z ? Kb : Qb;
#pragma unroll
    for (int mi = 0; mi < 4; mi++) {
      int r = r0 + mi * 16;
#pragma unroll
      for (int ni = 0; ni < 4; ni++) {
        int c = c0 + ni * 16;
#pragma unroll
        for (int j = 0; j < 4; j++)
          O[(size_t)(r + j) * 1024 + c] = f2bf(acc[mi][ni][j]);
      }
    }
  } else {
#pragma unroll
    for (int mi = 0; mi < 4; mi++) {
      int s0 = r0 + mi * 16;          // global row index (= b*2048 + s)
      int bb = s0 >> 11, sl = s0 & 2047;
#pragma unroll
      for (int ni = 0; ni < 4; ni++) {
        int d = c0 + ni * 16;
        u16x4 pk;
        pk.x = f2bf(acc[mi][ni][0]);
        pk.y = f2bf(acc[mi][ni][1]);
        pk.z = f2bf(acc[mi][ni][2]);
        pk.w = f2bf(acc[mi][ni][3]);
        *(u16x4*)(Vt + ((size_t)bb * 1024 + d) * 2048 + sl) = pk;
      }
    }
  }
}

// ---------------- scores = Q K^T / 32 (lower-tri tiles only) ----------------
__global__ __launch_bounds__(256) void kscores(const u16* __restrict__ Q,
                                               const u16* __restrict__ K,
                                               float* __restrict__ Sc) {
  const int tc = blockIdx.x, tr = blockIdx.y, b = blockIdx.z;
  if (tc > tr) return;
  __shared__ __align__(16) u16 As[4096];
  __shared__ __align__(16) u16 Bs[4096];
  const f32x4 z4 = {0.f, 0.f, 0.f, 0.f};
  f32x4 acc[4][4];
#pragma unroll
  for (int i = 0; i < 4; i++)
#pragma unroll
    for (int j = 0; j < 4; j++) acc[i][j] = z4;

  const u16* Qp = Q + (size_t)b * 2048 * 1024;
  const u16* Kp = K + (size_t)b * 2048 * 1024;
  gemm_inner(Qp, Kp, 1024, 1024, tr * 128, tc * 128, 32, As, Bs, acc);

  float* S = Sc + (size_t)b * 2048 * 2048;
  const int t = threadIdx.x, wid = t >> 6, lane = t & 63;
  const int wm = wid >> 1, wn = wid & 1;
  const int r0 = tr * 128 + wm * 64 + ((lane >> 4) * 4);
  const int c0 = tc * 128 + wn * 64 + (lane & 15);
#pragma unroll
  for (int mi = 0; mi < 4; mi++) {
    int r = r0 + mi * 16;
#pragma unroll
    for (int ni = 0; ni < 4; ni++) {
      int c = c0 + ni * 16;
#pragma unroll
      for (int j = 0; j < 4; j++)
        S[(size_t)(r + j) * 2048 + c] = acc[mi][ni][j] * 0.03125f;
    }
  }
}

// ---------------- row softmax -> P bf16 (zero-filled to tile ceiling) -------
__global__ __launch_bounds__(256) void ksoftmax(const float* __restrict__ Sc,
                                                u16* __restrict__ P) {
  const int i = blockIdx.x, b = blockIdx.y;
  const int nv = i + 1;
  const int nceil = ((i >> 7) + 1) << 7;
  const float* S = Sc + ((size_t)b * 2048 + i) * 2048;
  u16* Pr = P + ((size_t)b * 2048 + i) * 2048;
  __shared__ float srow[2048];
  __shared__ float red[4];
  const int t = threadIdx.x, lane = t & 63, wid = t >> 6;

  float lm = -3.0e38f;
  for (int j = t; j < nv; j += 256) {
    float v = S[j];
    srow[j] = v;
    lm = fmaxf(lm, v);
  }
#pragma unroll
  for (int o = 32; o > 0; o >>= 1) lm = fmaxf(lm, __shfl_down(lm, o));
  if (lane == 0) red[wid] = lm;
  __syncthreads();
  const float m = fmaxf(fmaxf(red[0], red[1]), fmaxf(red[2], red[3]));

  float ls = 0.f;
  for (int j = t; j < nv; j += 256) {
    float e = __expf(srow[j] - m);
    srow[j] = e;
    ls += e;
  }
#pragma unroll
  for (int o = 32; o > 0; o >>= 1) ls += __shfl_down(ls, o);
  __syncthreads();  // everyone done reading red[] for max
  if (lane == 0) red[wid] = ls;
  __syncthreads();
  const float inv = 1.f / (red[0] + red[1] + red[2] + red[3]);

  for (int j = t; j < nv; j += 256) Pr[j] = f2bf(srow[j] * inv);
  for (int j = nv + t; j < nceil; j += 256) Pr[j] = 0;
}

// ---------------- context = P V  (K-loop truncated causally) ----------------
__global__ __launch_bounds__(256) void kpv(const u16* __restrict__ P,
                                           const u16* __restrict__ Vt,
                                           float* __restrict__ Out) {
  const int bx = blockIdx.x;
  const int tr = 15 - blockIdx.y;  // biggest row-tiles dispatched first
  const int b = blockIdx.z;
  __shared__ __align__(16) u16 As[4096];
  __shared__ __align__(16) u16 Bs[4096];
  const f32x4 z4 = {0.f, 0.f, 0.f, 0.f};
  f32x4 acc[4][4];
#pragma unroll
  for (int i = 0; i < 4; i++)
#pragma unroll
    for (int j = 0; j < 4; j++) acc[i][j] = z4;

  const u16* Pp = P + (size_t)b * 2048 * 2048;
  const u16* Vp = Vt + (size_t)b * 1024 * 2048;
  gemm_inner(Pp, Vp, 2048, 2048, tr * 128, bx * 128, (tr + 1) * 4, As, Bs, acc);

  float* Ob = Out + (size_t)b * 2048 * 1024;
  const int t = threadIdx.x, wid = t >> 6, lane = t & 63;
  const int wm = wid >> 1, wn = wid & 1;
  const int r0 = tr * 128 + wm * 64 + ((lane >> 4) * 4);
  const int c0 = bx * 128 + wn * 64 + (lane & 15);
#pragma unroll
  for (int mi = 0; mi < 4; mi++) {
    int r = r0 + mi * 16;
#pragma unroll
    for (int ni = 0; ni < 4; ni++) {
      int c = c0 + ni * 16;
#pragma unroll
      for (int j = 0; j < 4; j++)
        Ob[(size_t)(r + j) * 1024 + c] = acc[mi][ni][j];
    }
  }
}

extern "C" void kernel_launch(void* const* d_in, const int* in_sizes, int n_in,
                              void* d_out, int out_size, void* d_ws,
                              size_t ws_size, hipStream_t stream) {
  const float* X = (const float*)d_in[0];
  const float* Wq = (const float*)d_in[1];
  const float* Wk = (const float*)d_in[2];
  const float* Wv = (const float*)d_in[3];
  float* Out = (float*)d_out;

  char* ws = (char*)d_ws;
  u16* Xb = (u16*)(ws);                     // 16 MB  bf16 X
  u16* Wt = (u16*)(ws + 16777216);          //  6 MB  bf16 W^T x3
  u16* Qb = (u16*)(ws + 23068672);          // 16 MB
  u16* Kb = (u16*)(ws + 39845888);          // 16 MB
  u16* Vt = (u16*)(ws + 56623104);          // 16 MB  V transposed per batch
  float* Sc = (float*)(ws + 73400320);      // 64 MB  fp32 scores
  u16* P = (u16*)(ws + 140509184);          // 32 MB  bf16 probs
  // total 174,063,616 bytes

  kconv_x<<<8192, 256, 0, stream>>>(X, Xb);
  kconv_wt<<<dim3(32, 32, 3), dim3(32, 8), 0, stream>>>(Wq, Wk, Wv, Wt);
  kqkv<<<dim3(8, 64, 3), 256, 0, stream>>>(Xb, Wt, Qb, Kb, Vt);
  kscores<<<dim3(16, 16, 4), 256, 0, stream>>>(Qb, Kb, Sc);
  ksoftmax<<<dim3(2048, 4), 256, 0, stream>>>(Sc, P);
  kpv<<<dim3(8, 16, 4), 256, 0, stream>>>(P, Vt, Out);
}

// Round 4
// 192.368 us; speedup vs baseline: 1.1395x; 1.1395x over previous
//
#include <hip/hip_runtime.h>

typedef unsigned short u16;
typedef __attribute__((ext_vector_type(8))) short short8;
typedef __attribute__((ext_vector_type(4))) float f32x4;
typedef __attribute__((ext_vector_type(4))) unsigned short u16x4;
typedef __attribute__((ext_vector_type(4))) float float4v;

__device__ __forceinline__ u16 f2bf(float f) {
  union { float f; unsigned u; } v; v.f = f;
  unsigned r = v.u + 0x7FFFu + ((v.u >> 16) & 1u);
  return (u16)(r >> 16);
}

__device__ __forceinline__ void gload16(const void* g, void* l) {
  __builtin_amdgcn_global_load_lds(
      (const __attribute__((address_space(1))) unsigned int*)g,
      (__attribute__((address_space(3))) unsigned int*)l, 16, 0, 0);
}

// ---------------- conversion kernels ----------------

// X fp32 [8192,1024] -> bf16 linear
__global__ __launch_bounds__(256) void kconv_x(const float* __restrict__ X,
                                               u16* __restrict__ Xb) {
  size_t i = ((size_t)blockIdx.x * 256 + threadIdx.x) * 4;
  float4v v = *(const float4v*)(X + i);
  u16x4 o;
  o.x = f2bf(v.x); o.y = f2bf(v.y); o.z = f2bf(v.z); o.w = f2bf(v.w);
  *(u16x4*)(Xb + i) = o;
}

// W fp32 [K=1024][N=1024] -> Wt bf16 [N][K], z selects Wq/Wk/Wv
__global__ __launch_bounds__(256) void kconv_wt(const float* __restrict__ Wq,
                                                const float* __restrict__ Wk,
                                                const float* __restrict__ Wv,
                                                u16* __restrict__ Wt) {
  __shared__ float tile[32][33];
  const float* W = blockIdx.z == 0 ? Wq : (blockIdx.z == 1 ? Wk : Wv);
  u16* O = Wt + (size_t)blockIdx.z * 1024 * 1024;
  int tx = threadIdx.x, ty = threadIdx.y;
  int n0 = blockIdx.x * 32, k0 = blockIdx.y * 32;
#pragma unroll
  for (int r = 0; r < 32; r += 8)
    tile[ty + r][tx] = W[(size_t)(k0 + ty + r) * 1024 + n0 + tx];
  __syncthreads();
#pragma unroll
  for (int r = 0; r < 32; r += 8)
    O[(size_t)(n0 + ty + r) * 1024 + k0 + tx] = f2bf(tile[tx][ty + r]);
}

// ---------------- GEMM core (m97 structure) ----------------
// C[128x128] += A[M,K] * Bt[N,K]^T  ; BK=32, 256 threads = 4 waves (2x2),
// each wave 64x64 as 4x4 frags of mfma_f32_16x16x32_bf16.
__device__ __forceinline__ void gemm_inner(const u16* __restrict__ A,
                                           const u16* __restrict__ B,
                                           int lda, int ldb,
                                           int rowBase, int colBase, int kIters,
                                           u16* As, u16* Bs, f32x4 acc[4][4]) {
  const int t = threadIdx.x;
  const int wid = t >> 6, lane = t & 63;
  const int wm = wid >> 1, wn = wid & 1;
  const int lrow = lane & 15, kseg = (lane >> 4) * 8;
  const u16* ga = A + (size_t)(rowBase + (t >> 2)) * lda + ((t & 3) * 8);
  const u16* gb = B + (size_t)(colBase + (t >> 2)) * ldb + ((t & 3) * 8);
  u16* la0 = As + wid * 512;
  u16* la1 = As + 2048 + wid * 512;
  u16* lb0 = Bs + wid * 512;
  u16* lb1 = Bs + 2048 + wid * 512;
  const size_t a64 = (size_t)64 * lda, b64 = (size_t)64 * ldb;

  for (int kt = 0; kt < kIters; ++kt) {
    const int k0 = kt * 32;
    gload16(ga + k0, la0);
    gload16(ga + a64 + k0, la1);
    gload16(gb + k0, lb0);
    gload16(gb + b64 + k0, lb1);
    __syncthreads();
    short8 a[4], b[4];
#pragma unroll
    for (int mi = 0; mi < 4; mi++)
      a[mi] = *(const short8*)(As + (wm * 64 + mi * 16 + lrow) * 32 + kseg);
#pragma unroll
    for (int ni = 0; ni < 4; ni++)
      b[ni] = *(const short8*)(Bs + (wn * 64 + ni * 16 + lrow) * 32 + kseg);
#pragma unroll
    for (int mi = 0; mi < 4; mi++)
#pragma unroll
      for (int ni = 0; ni < 4; ni++)
        acc[mi][ni] = __builtin_amdgcn_mfma_f32_16x16x32_bf16(
            a[mi], b[ni], acc[mi][ni], 0, 0, 0);
    __syncthreads();
  }
}

// ---------------- QKV projection ----------------
// 1536 linear blocks, XCD-chunked: XCD owns 8 row-tiles, (col,z) outer,
// row inner -> X tile (2MB) resident in per-XCD L2, reused 24x.
__global__ __launch_bounds__(256) void kqkv(const u16* __restrict__ Xb,
                                            const u16* __restrict__ Wt,
                                            u16* __restrict__ Qb,
                                            u16* __restrict__ Kb,
                                            u16* __restrict__ Vt) {
  __shared__ __align__(16) u16 As[4096];
  __shared__ __align__(16) u16 Bs[4096];
  const f32x4 z4 = {0.f, 0.f, 0.f, 0.f};
  f32x4 acc[4][4];
#pragma unroll
  for (int i = 0; i < 4; i++)
#pragma unroll
    for (int j = 0; j < 4; j++) acc[i][j] = z4;

  const int l = blockIdx.x;
  const int xcd = l & 7, idx = l >> 3;    // idx 0..191
  const int cz = idx >> 3, rloc = idx & 7; // cz 0..23 outer, row inner
  const int rowTile = xcd * 8 + rloc;      // 0..63
  const int z = cz >> 3, colTile = cz & 7; // z 0..2, col 0..7

  const int rowBase = rowTile * 128, colBase = colTile * 128;
  const u16* Bt = Wt + (size_t)z * 1024 * 1024;
  gemm_inner(Xb, Bt, 1024, 1024, rowBase, colBase, 32, As, Bs, acc);

  const int t = threadIdx.x, wid = t >> 6, lane = t & 63;
  const int wm = wid >> 1, wn = wid & 1;
  const int r0 = rowBase + wm * 64 + ((lane >> 4) * 4);
  const int c0 = colBase + wn * 64 + (lane & 15);
  if (z < 2) {
    u16* O = z ? Kb : Qb;
#pragma unroll
    for (int mi = 0; mi < 4; mi++) {
      int r = r0 + mi * 16;
#pragma unroll
      for (int ni = 0; ni < 4; ni++) {
        int c = c0 + ni * 16;
#pragma unroll
        for (int j = 0; j < 4; j++)
          O[(size_t)(r + j) * 1024 + c] = f2bf(acc[mi][ni][j]);
      }
    }
  } else {
#pragma unroll
    for (int mi = 0; mi < 4; mi++) {
      int s0 = r0 + mi * 16;          // global row index (= b*2048 + s)
      int bb = s0 >> 11, sl = s0 & 2047;
#pragma unroll
      for (int ni = 0; ni < 4; ni++) {
        int d = c0 + ni * 16;
        u16x4 pk;
        pk.x = f2bf(acc[mi][ni][0]);
        pk.y = f2bf(acc[mi][ni][1]);
        pk.z = f2bf(acc[mi][ni][2]);
        pk.w = f2bf(acc[mi][ni][3]);
        *(u16x4*)(Vt + ((size_t)bb * 1024 + d) * 2048 + sl) = pk;
      }
    }
  }
}

// ---------------- scores = Q K^T / 32 (lower-tri tiles only) ----------------
// 136 tri-tiles per batch, 17 per XCD (equal work, contiguous tr ranges).
__global__ __launch_bounds__(256) void kscores(const u16* __restrict__ Q,
                                               const u16* __restrict__ K,
                                               float* __restrict__ Sc) {
  const int x = blockIdx.x, b = blockIdx.y;
  const int xcd = x & 7, idx = x >> 3;   // idx 0..16
  const int tid = xcd * 17 + idx;        // 0..135
  int tr = (int)((sqrtf(8.f * tid + 1.f) - 1.f) * 0.5f);
  while ((tr + 1) * (tr + 2) / 2 <= tid) ++tr;
  while (tr * (tr + 1) / 2 > tid) --tr;
  const int tc = tid - tr * (tr + 1) / 2;

  __shared__ __align__(16) u16 As[4096];
  __shared__ __align__(16) u16 Bs[4096];
  const f32x4 z4 = {0.f, 0.f, 0.f, 0.f};
  f32x4 acc[4][4];
#pragma unroll
  for (int i = 0; i < 4; i++)
#pragma unroll
    for (int j = 0; j < 4; j++) acc[i][j] = z4;

  const u16* Qp = Q + (size_t)b * 2048 * 1024;
  const u16* Kp = K + (size_t)b * 2048 * 1024;
  gemm_inner(Qp, Kp, 1024, 1024, tr * 128, tc * 128, 32, As, Bs, acc);

  float* S = Sc + (size_t)b * 2048 * 2048;
  const int t = threadIdx.x, wid = t >> 6, lane = t & 63;
  const int wm = wid >> 1, wn = wid & 1;
  const int r0 = tr * 128 + wm * 64 + ((lane >> 4) * 4);
  const int c0 = tc * 128 + wn * 64 + (lane & 15);
#pragma unroll
  for (int mi = 0; mi < 4; mi++) {
    int r = r0 + mi * 16;
#pragma unroll
    for (int ni = 0; ni < 4; ni++) {
      int c = c0 + ni * 16;
#pragma unroll
      for (int j = 0; j < 4; j++)
        S[(size_t)(r + j) * 2048 + c] = acc[mi][ni][j] * 0.03125f;
    }
  }
}

// ---------------- row softmax -> P bf16 (zero-filled to tile ceiling) -------
__global__ __launch_bounds__(256) void ksoftmax(const float* __restrict__ Sc,
                                                u16* __restrict__ P) {
  const int i = blockIdx.x, b = blockIdx.y;
  const int nv = i + 1;
  const int nceil = ((i >> 7) + 1) << 7;
  const float* S = Sc + ((size_t)b * 2048 + i) * 2048;
  u16* Pr = P + ((size_t)b * 2048 + i) * 2048;
  __shared__ float srow[2048];
  __shared__ float red[4];
  const int t = threadIdx.x, lane = t & 63, wid = t >> 6;

  float lm = -3.0e38f;
  for (int j = t; j < nv; j += 256) {
    float v = S[j];
    srow[j] = v;
    lm = fmaxf(lm, v);
  }
#pragma unroll
  for (int o = 32; o > 0; o >>= 1) lm = fmaxf(lm, __shfl_down(lm, o));
  if (lane == 0) red[wid] = lm;
  __syncthreads();
  const float m = fmaxf(fmaxf(red[0], red[1]), fmaxf(red[2], red[3]));

  float ls = 0.f;
  for (int j = t; j < nv; j += 256) {
    float e = __expf(srow[j] - m);
    srow[j] = e;
    ls += e;
  }
#pragma unroll
  for (int o = 32; o > 0; o >>= 1) ls += __shfl_down(ls, o);
  __syncthreads();
  if (lane == 0) red[wid] = ls;
  __syncthreads();
  const float inv = 1.f / (red[0] + red[1] + red[2] + red[3]);

  for (int j = t; j < nv; j += 256) Pr[j] = f2bf(srow[j] * inv);
  for (int j = nv + t; j < nceil; j += 256) Pr[j] = 0;
}

// ---------------- context = P V  (K-loop truncated causally) ----------------
// 128 blocks/batch; XCD pairs tr=xcd with tr=15-xcd -> equal causal work/XCD.
__global__ __launch_bounds__(256) void kpv(const u16* __restrict__ P,
                                           const u16* __restrict__ Vt,
                                           float* __restrict__ Out) {
  const int x = blockIdx.x, b = blockIdx.y;
  const int xcd = x & 7, idx = x >> 3;       // idx 0..15
  const int tr = (idx < 8) ? xcd : (15 - xcd);
  const int col = idx & 7;

  __shared__ __align__(16) u16 As[4096];
  __shared__ __align__(16) u16 Bs[4096];
  const f32x4 z4 = {0.f, 0.f, 0.f, 0.f};
  f32x4 acc[4][4];
#pragma unroll
  for (int i = 0; i < 4; i++)
#pragma unroll
    for (int j = 0; j < 4; j++) acc[i][j] = z4;

  const u16* Pp = P + (size_t)b * 2048 * 2048;
  const u16* Vp = Vt + (size_t)b * 1024 * 2048;
  gemm_inner(Pp, Vp, 2048, 2048, tr * 128, col * 128, (tr + 1) * 4, As, Bs, acc);

  float* Ob = Out + (size_t)b * 2048 * 1024;
  const int t = threadIdx.x, wid = t >> 6, lane = t & 63;
  const int wm = wid >> 1, wn = wid & 1;
  const int r0 = tr * 128 + wm * 64 + ((lane >> 4) * 4);
  const int c0 = col * 128 + wn * 64 + (lane & 15);
#pragma unroll
  for (int mi = 0; mi < 4; mi++) {
    int r = r0 + mi * 16;
#pragma unroll
    for (int ni = 0; ni < 4; ni++) {
      int c = c0 + ni * 16;
#pragma unroll
      for (int j = 0; j < 4; j++)
        Ob[(size_t)(r + j) * 1024 + c] = acc[mi][ni][j];
    }
  }
}

extern "C" void kernel_launch(void* const* d_in, const int* in_sizes, int n_in,
                              void* d_out, int out_size, void* d_ws,
                              size_t ws_size, hipStream_t stream) {
  const float* X = (const float*)d_in[0];
  const float* Wq = (const float*)d_in[1];
  const float* Wk = (const float*)d_in[2];
  const float* Wv = (const float*)d_in[3];
  float* Out = (float*)d_out;

  char* ws = (char*)d_ws;
  u16* Xb = (u16*)(ws);                     // 16 MB  bf16 X
  u16* Wt = (u16*)(ws + 16777216);          //  6 MB  bf16 W^T x3
  u16* Qb = (u16*)(ws + 23068672);          // 16 MB
  u16* Kb = (u16*)(ws + 39845888);          // 16 MB
  u16* Vt = (u16*)(ws + 56623104);          // 16 MB  V transposed per batch
  float* Sc = (float*)(ws + 73400320);      // 64 MB  fp32 scores
  u16* P = (u16*)(ws + 140509184);          // 32 MB  bf16 probs
  // total 174,063,616 bytes

  kconv_x<<<8192, 256, 0, stream>>>(X, Xb);
  kconv_wt<<<dim3(32, 32, 3), dim3(32, 8), 0, stream>>>(Wq, Wk, Wv, Wt);
  kqkv<<<1536, 256, 0, stream>>>(Xb, Wt, Qb, Kb, Vt);
  kscores<<<dim3(136, 4), 256, 0, stream>>>(Qb, Kb, Sc);
  ksoftmax<<<dim3(2048, 4), 256, 0, stream>>>(Sc, P);
  kpv<<<dim3(128, 4), 256, 0, stream>>>(P, Vt, Out);
}